// Round 1
// baseline (77.770 us; speedup 1.0000x reference)
//
#include <hip/hip_runtime.h>
#include <hip/hip_bf16.h>

#define N 8192
#define DIMS 128
#define NSLICE 16
#define SLICE_COLS (N / NSLICE)     // 512
#define SUBTILES (SLICE_COLS / 16)  // 32
#define ROWS_PER_BLOCK 256
#define NROWBLK (N / ROWS_PER_BLOCK)  // 32
#define MARGIN_F 0.2f
#define EPS_F 1e-6f
#define INF_F __builtin_huge_valf()

typedef __bf16 bf16x8 __attribute__((ext_vector_type(8)));
typedef float f32x4 __attribute__((ext_vector_type(4)));

// ws layout (bytes):
//   Xb   : ushort[N*DIMS]      @ 0          (2 MiB)   bf16 features
//   meta : float2[N]           @ 2097152    (64 KiB)  {sq, label bits}
//   part : float4[NSLICE*N]    @ 2162688    (2 MiB)   per-slice {bpv, bpi, bnv, bni}
//   bsum : float2[NROWBLK]     @ 4259840    (256 B)
#define XB_OFF   0
#define META_OFF 2097152
#define PART_OFF 2162688
#define BSUM_OFF 4259840

// ---------------- prep: fp32 -> bf16, row sq-norm, pack label -------------
__global__ __launch_bounds__(256) void prep_kernel(
    const float* __restrict__ feat, const int* __restrict__ lab,
    unsigned short* __restrict__ Xb, float2* __restrict__ meta) {
  int row = blockIdx.x * 4 + (threadIdx.x >> 6);
  int lane = threadIdx.x & 63;
  float2 x = *reinterpret_cast<const float2*>(feat + (size_t)row * DIMS + lane * 2);
  __hip_bfloat16 hx = __float2bfloat16(x.x);
  __hip_bfloat16 hy = __float2bfloat16(x.y);
  unsigned short ux, uy;
  __builtin_memcpy(&ux, &hx, 2);
  __builtin_memcpy(&uy, &hy, 2);
  unsigned int packed = (unsigned int)ux | ((unsigned int)uy << 16);
  *reinterpret_cast<unsigned int*>(Xb + (size_t)row * DIMS + lane * 2) = packed;
  float s = x.x * x.x + x.y * x.y;
#pragma unroll
  for (int m = 32; m >= 1; m >>= 1) s += __shfl_xor(s, m, 64);
  if (lane == 0) meta[row] = make_float2(s, __int_as_float(lab[row]));
}

// ---------------- mine: fused bf16 MFMA GEMM + batch-hard mining ----------
// grid = NROWBLK * NSLICE blocks, 256 threads (4 waves).
// Each wave owns 64 anchor rows (4 strips of 16); scans SLICE_COLS columns.
__global__ __launch_bounds__(256, 2) void mine_kernel(
    const unsigned short* __restrict__ Xb, const float2* __restrict__ meta,
    const int* __restrict__ lab, float4* __restrict__ part) {
  int rb = blockIdx.x / NSLICE;
  int sl = blockIdx.x % NSLICE;
  int wave = threadIdx.x >> 6;
  int lane = threadIdx.x & 63;
  int lrow = lane & 15;   // A-row / B-col / C-col lane index
  int lk = lane >> 4;     // k-subgroup; also C-row group
  int rowbase = rb * ROWS_PER_BLOCK + wave * 64;

  // A fragments: 4 strips x 4 k-groups, held in registers for the whole scan
  bf16x8 afrag[4][4];
#pragma unroll
  for (int s = 0; s < 4; ++s) {
    const unsigned short* rp = Xb + (size_t)(rowbase + s * 16 + lrow) * DIMS;
#pragma unroll
    for (int g = 0; g < 4; ++g)
      afrag[s][g] = *reinterpret_cast<const bf16x8*>(rp + g * 32 + lk * 8);
  }
  // labels of the 4 epilogue rows per strip (C rows = lk*4 + e)
  int4 labi[4];
#pragma unroll
  for (int s = 0; s < 4; ++s)
    labi[s] = *reinterpret_cast<const int4*>(lab + rowbase + s * 16 + lk * 4);

  float bpv[4][4], bnv[4][4];
  int bpi[4][4], bni[4][4];
#pragma unroll
  for (int s = 0; s < 4; ++s)
#pragma unroll
    for (int e = 0; e < 4; ++e) {
      bpv[s][e] = -INF_F; bnv[s][e] = INF_F; bpi[s][e] = 0; bni[s][e] = 0;
    }

  int j0 = sl * SLICE_COLS;
  // software pipeline: prefetch subtile t+1 while computing t
  float2 mcur = meta[j0 + lrow];
  bf16x8 bcur[4];
  {
    const unsigned short* cp = Xb + (size_t)(j0 + lrow) * DIMS;
#pragma unroll
    for (int g = 0; g < 4; ++g)
      bcur[g] = *reinterpret_cast<const bf16x8*>(cp + g * 32 + lk * 8);
  }

  for (int t = 0; t < SUBTILES; ++t) {
    int tn = (t + 1 < SUBTILES) ? (t + 1) : t;
    int jn = j0 + tn * 16 + lrow;
    float2 mnext = meta[jn];
    bf16x8 bnext[4];
    {
      const unsigned short* cp = Xb + (size_t)jn * DIMS;
#pragma unroll
      for (int g = 0; g < 4; ++g)
        bnext[g] = *reinterpret_cast<const bf16x8*>(cp + g * 32 + lk * 8);
    }

    int jcur = j0 + t * 16 + lrow;
    float sqj = mcur.x;
    int labj = __float_as_int(mcur.y);

#pragma unroll
    for (int s = 0; s < 4; ++s) {
      f32x4 acc = {0.f, 0.f, 0.f, 0.f};
#pragma unroll
      for (int g = 0; g < 4; ++g)
        acc = __builtin_amdgcn_mfma_f32_16x16x32_bf16(afrag[s][g], bcur[g], acc, 0, 0, 0);
      int labs0 = labi[s].x, labs1 = labi[s].y, labs2 = labi[s].z, labs3 = labi[s].w;
      int labs[4] = {labs0, labs1, labs2, labs3};
#pragma unroll
      for (int e = 0; e < 4; ++e) {
        float key = fmaf(-2.0f, acc[e], sqj);
        bool pos = (labj == labs[e]);
        float keyp = pos ? key : -INF_F;
        float keyn = pos ? INF_F : key;
        bool gp = keyp > bpv[s][e];
        bpv[s][e] = gp ? keyp : bpv[s][e];
        bpi[s][e] = gp ? jcur : bpi[s][e];
        bool gn = keyn < bnv[s][e];
        bnv[s][e] = gn ? keyn : bnv[s][e];
        bni[s][e] = gn ? jcur : bni[s][e];
      }
    }

    mcur = mnext;
#pragma unroll
    for (int g = 0; g < 4; ++g) bcur[g] = bnext[g];
  }

  // merge across the 16 lanes that share each C-row (lane bits 0-3)
#pragma unroll
  for (int s = 0; s < 4; ++s) {
#pragma unroll
    for (int e = 0; e < 4; ++e) {
      float pv = bpv[s][e]; int pi = bpi[s][e];
      float nv = bnv[s][e]; int ni = bni[s][e];
#pragma unroll
      for (int m = 1; m < 16; m <<= 1) {
        float opv = __shfl_xor(pv, m, 64); int opi = __shfl_xor(pi, m, 64);
        float onv = __shfl_xor(nv, m, 64); int oni = __shfl_xor(ni, m, 64);
        bool tp = (opv > pv) || (opv == pv && opi < pi);
        pv = tp ? opv : pv; pi = tp ? opi : pi;
        bool tn = (onv < nv) || (onv == nv && oni < ni);
        nv = tn ? onv : nv; ni = tn ? oni : ni;
      }
      if (lrow == 0) {
        int row = rowbase + s * 16 + lk * 4 + e;
        part[(size_t)sl * N + row] =
            make_float4(pv, __int_as_float(pi), nv, __int_as_float(ni));
      }
    }
  }
}

// ---------------- finalize: merge slices, exact fp32 distances, hinge ------
__global__ __launch_bounds__(256) void finalize_kernel(
    const float* __restrict__ feat, const float4* __restrict__ part,
    float2* __restrict__ bsum) {
  int i = blockIdx.x * 256 + threadIdx.x;
  float bpv = -INF_F, bnv = INF_F;
  int bpi = 0, bni = 0;
#pragma unroll
  for (int sl = 0; sl < NSLICE; ++sl) {
    float4 p = part[(size_t)sl * N + i];
    if (p.x > bpv) { bpv = p.x; bpi = __float_as_int(p.y); }
    if (p.z < bnv) { bnv = p.z; bni = __float_as_int(p.w); }
  }
  bool valid = (bnv < INF_F);

  const float4* a = reinterpret_cast<const float4*>(feat + (size_t)i * DIMS);
  const float4* pp = reinterpret_cast<const float4*>(feat + (size_t)bpi * DIMS);
  const float4* nn = reinterpret_cast<const float4*>(feat + (size_t)bni * DIMS);
  float sp = 0.f, sn = 0.f;
#pragma unroll
  for (int k = 0; k < DIMS / 4; ++k) {
    float4 av = a[k], pv = pp[k], nv = nn[k];
    float d0 = av.x - pv.x + EPS_F; sp = fmaf(d0, d0, sp);
    float d1 = av.y - pv.y + EPS_F; sp = fmaf(d1, d1, sp);
    float d2 = av.z - pv.z + EPS_F; sp = fmaf(d2, d2, sp);
    float d3 = av.w - pv.w + EPS_F; sp = fmaf(d3, d3, sp);
    float e0 = av.x - nv.x + EPS_F; sn = fmaf(e0, e0, sn);
    float e1 = av.y - nv.y + EPS_F; sn = fmaf(e1, e1, sn);
    float e2 = av.z - nv.z + EPS_F; sn = fmaf(e2, e2, sn);
    float e3 = av.w - nv.w + EPS_F; sn = fmaf(e3, e3, sn);
  }
  float per = sqrtf(sp) - sqrtf(sn) + MARGIN_F;
  per = per > 0.f ? per : 0.f;
  per = valid ? per : 0.f;
  float c = valid ? 1.f : 0.f;

#pragma unroll
  for (int m = 32; m >= 1; m >>= 1) {
    per += __shfl_xor(per, m, 64);
    c += __shfl_xor(c, m, 64);
  }
  __shared__ float s_s[4], s_c[4];
  int wave = threadIdx.x >> 6, lane = threadIdx.x & 63;
  if (lane == 0) { s_s[wave] = per; s_c[wave] = c; }
  __syncthreads();
  if (threadIdx.x == 0) {
    float ts = 0.f, tc = 0.f;
#pragma unroll
    for (int w = 0; w < 4; ++w) { ts += s_s[w]; tc += s_c[w]; }
    bsum[blockIdx.x] = make_float2(ts, tc);
  }
}

__global__ __launch_bounds__(64) void final_reduce_kernel(
    const float2* __restrict__ bsum, float* __restrict__ out) {
  int t = threadIdx.x;
  float s = 0.f, c = 0.f;
  if (t < NROWBLK) { float2 v = bsum[t]; s = v.x; c = v.y; }
#pragma unroll
  for (int m = 32; m >= 1; m >>= 1) {
    s += __shfl_xor(s, m, 64);
    c += __shfl_xor(c, m, 64);
  }
  if (t == 0) out[0] = (c > 0.f) ? (s / c) : 0.f;
}

extern "C" void kernel_launch(void* const* d_in, const int* in_sizes, int n_in,
                              void* d_out, int out_size, void* d_ws, size_t ws_size,
                              hipStream_t stream) {
  const float* feat = (const float*)d_in[0];
  const int* lab = (const int*)d_in[1];
  char* ws = (char*)d_ws;
  unsigned short* Xb = (unsigned short*)(ws + XB_OFF);
  float2* meta = (float2*)(ws + META_OFF);
  float4* part = (float4*)(ws + PART_OFF);
  float2* bsum = (float2*)(ws + BSUM_OFF);
  float* out = (float*)d_out;

  prep_kernel<<<N / 4, 256, 0, stream>>>(feat, lab, Xb, meta);
  mine_kernel<<<NROWBLK * NSLICE, 256, 0, stream>>>(Xb, meta, lab, part);
  finalize_kernel<<<N / 256, 256, 0, stream>>>(feat, part, bsum);
  final_reduce_kernel<<<1, 64, 0, stream>>>(bsum, out);
}